// Round 7
// baseline (448.317 us; speedup 1.0000x reference)
//
#include <hip/hip_runtime.h>
#include <hip/hip_cooperative_groups.h>

namespace cg = cooperative_groups;

#define DECAY_F 0.99f
#define OMD_F   0.01f
#define EPS_F   1e-5f

typedef __attribute__((ext_vector_type(8))) __bf16 bf16x8;
typedef __attribute__((ext_vector_type(4))) float  f32x4;

// ---------------- ws layout (byte offsets) ----------------
#define WSB_CNTI     0          // 1024 i32 (zeroed in esplit)
#define WSB_LOSS     4096       // 256 f32  (zeroed in esplit)
#define WSB_DWACC    8192       // 262144 f32, 1 MB (zeroed in esplit)
#define WSB_CSUM     1056768    // 1 f32 (written in tail scan)
#define WSB_ENORM    1056832    // 1024 f32
#define WSB_IDX      1060928    // 32768 i32
#define WSB_EHI      1192000    // 262144 ushort
#define WSB_ELO      1716288    // 262144 ushort
#define WSB_SORT     2240576    // 32768 i32
#define WSB_CURS     2371648    // 1024 i32
#define WSB_BESTD    2375744    // 4*32768 f32
#define WSB_BESTI    2900032    // 4*32768 i32 (end 3424320)

// ---------------- out layout (float offsets) ----------------
#define OUT_ZQ    0
#define OUT_LOSS  8388608
#define OUT_IDX   8388609
#define OUT_EMB   8421377
#define OUT_CS    8683521
#define OUT_EMAW  8684545

// ---------- bf16 split helpers (RNE, no NaN inputs) ----------
__device__ __forceinline__ unsigned short f2bf(float x) {
    unsigned u = __builtin_bit_cast(unsigned, x);
    u += 0x7fffu + ((u >> 16) & 1u);
    return (unsigned short)(u >> 16);
}
__device__ __forceinline__ float bf2f(unsigned short h) {
    return __builtin_bit_cast(float, (unsigned)h << 16);
}
__device__ __forceinline__ void split8(const float4 a, const float4 b,
                                       uint4& hi, uint4& lo) {
    float f[8] = {a.x, a.y, a.z, a.w, b.x, b.y, b.z, b.w};
    unsigned short h[8], l[8];
    #pragma unroll
    for (int i = 0; i < 8; ++i) {
        h[i] = f2bf(f[i]);
        l[i] = f2bf(f[i] - bf2f(h[i]));
    }
    hi.x = (unsigned)h[0] | ((unsigned)h[1] << 16);
    hi.y = (unsigned)h[2] | ((unsigned)h[3] << 16);
    hi.z = (unsigned)h[4] | ((unsigned)h[5] << 16);
    hi.w = (unsigned)h[6] | ((unsigned)h[7] << 16);
    lo.x = (unsigned)l[0] | ((unsigned)l[1] << 16);
    lo.y = (unsigned)l[2] | ((unsigned)l[3] << 16);
    lo.z = (unsigned)l[4] | ((unsigned)l[5] << 16);
    lo.w = (unsigned)l[6] | ((unsigned)l[7] << 16);
}

// ---------- global -> LDS direct 16B copy ----------
__device__ __forceinline__ void load_lds16(const void* g, void* l) {
    __builtin_amdgcn_global_load_lds(
        (const __attribute__((address_space(1))) unsigned int*)g,
        (__attribute__((address_space(3))) unsigned int*)l, 16, 0, 0);
}

// ============ kernel 0: esplit + enorm + zero ws accumulators ============
__global__ __launch_bounds__(256)
void esplit_enorm_kernel(const float* __restrict__ emb,
                         unsigned short* __restrict__ e_hi,
                         unsigned short* __restrict__ e_lo,
                         float* __restrict__ enorm,
                         int* __restrict__ cnt, float* __restrict__ lossbuf,
                         float* __restrict__ dwacc) {
    const int tid = threadIdx.x, lane = tid & 63, wv = tid >> 6;
    const int gtid = blockIdx.x * 256 + tid;          // 0..65535
    // zero accumulators for the tail pipeline (replaces hipMemsetAsync)
    *(float4*)(dwacc + (size_t)gtid * 4) = make_float4(0.f, 0.f, 0.f, 0.f);
    if (gtid < 1024) cnt[gtid] = 0;
    if (gtid < 256)  lossbuf[gtid] = 0.f;

    const int k = blockIdx.x * 4 + wv;
    const float4 v = *(const float4*)(emb + (size_t)k * 256 + lane * 4);
    float f[4] = {v.x, v.y, v.z, v.w};
    unsigned short h[4], l[4];
    #pragma unroll
    for (int i = 0; i < 4; ++i) { h[i] = f2bf(f[i]); l[i] = f2bf(f[i] - bf2f(h[i])); }
    uint2 hi, lo;
    hi.x = (unsigned)h[0] | ((unsigned)h[1] << 16);
    hi.y = (unsigned)h[2] | ((unsigned)h[3] << 16);
    lo.x = (unsigned)l[0] | ((unsigned)l[1] << 16);
    lo.y = (unsigned)l[2] | ((unsigned)l[3] << 16);
    *(uint2*)(e_hi + (size_t)k * 256 + lane * 4) = hi;
    *(uint2*)(e_lo + (size_t)k * 256 + lane * 4) = lo;
    float s = v.x * v.x + v.y * v.y + v.z * v.z + v.w * v.w;
    #pragma unroll
    for (int off = 32; off > 0; off >>= 1) s += __shfl_down(s, off);
    if (lane == 0) enorm[k] = s;
}

// ============ kernel 1: MFMA argmin — round-5 structure + B double-buffer ============
// Grid 1024 = 256 row-groups x 4 code-splits. Block 128 rows x 256 codes,
// 4 waves (2x2), wave tile 64x128 = 4x8 of 16x16x32 MFMAs, kc=8 over D=256.
// 3-combo bf16 hi/lo split. B double-buffered in LDS (80 KB dynamic);
// global_load_lds for kc+1 issued at TOP of kc's compute, so the vmcnt(0)
// drain at the next barrier lands after ~96 MFMAs of latency cover.
__global__ __launch_bounds__(256, 2)
void argmin_kernel(const float* __restrict__ z,
                   const unsigned short* __restrict__ e_hi,
                   const unsigned short* __restrict__ e_lo,
                   const float* __restrict__ enorm,
                   float* __restrict__ best_d, int* __restrict__ best_i) {
    extern __shared__ unsigned short smem[];
    unsigned short* Ah = smem;            // 4096 halfs
    unsigned short* Al = smem + 4096;     // 4096
    unsigned short* BhB = smem + 8192;    // 2 bufs x 8192 halfs
    unsigned short* BlB = smem + 24576;   // 2 bufs x 8192 halfs (total 81920 B)

    const int tid  = threadIdx.x;
    const int lane = tid & 63;
    const int wv   = tid >> 6;
    const int wy   = wv >> 1, wx = wv & 1;
    const int tx   = lane & 15, quad = lane >> 4;
    const int rowg = blockIdx.x & 255;
    const int csp  = blockIdx.x >> 8;
    const int row0 = rowg * 128;
    const int col0 = csp * 256;

    // ---- A staging map (2 granules of 8 floats per thread) ----
    const int rA0 = tid >> 2,         gA0 = tid & 3;
    const int rA1 = (tid + 256) >> 2, gA1 = (tid + 256) & 3;
    const float* zA0 = z + (size_t)(row0 + rA0) * 256 + gA0 * 8;
    const float* zA1 = z + (size_t)(row0 + rA1) * 256 + gA1 * 8;
    const int offA0 = rA0 * 32 + ((gA0 ^ (rA0 & 3)) << 3);
    const int offA1 = rA1 * 32 + ((gA1 ^ (rA1 & 3)) << 3);

    // ---- B staging: lane-linear LDS; swizzle folded into GLOBAL granule ----
    size_t gBh[4], gBl[4]; int lBo[4];
    #pragma unroll
    for (int i = 0; i < 4; ++i) {
        const int s  = i * 256 + wv * 64 + lane;
        const int c  = s >> 2, gs = s & 3;
        const int g  = gs ^ (c & 3);
        gBh[i] = (size_t)(col0 + c) * 256 + g * 8;
        gBl[i] = gBh[i];
        lBo[i] = (i * 256 + wv * 64) * 8;             // wave-uniform base (halfs)
    }

    // ---- frag read offsets (halfs, swizzled) ----
    int offAf[4], offBf[8];
    #pragma unroll
    for (int i = 0; i < 4; ++i) {
        const int rt = wy * 64 + i * 16 + tx;
        offAf[i] = rt * 32 + ((quad ^ (rt & 3)) << 3);
    }
    #pragma unroll
    for (int j = 0; j < 8; ++j) {
        const int cb = wx * 128 + j * 16 + tx;
        offBf[j] = cb * 32 + ((quad ^ (cb & 3)) << 3);
    }

    f32x4 acc[4][8];
    #pragma unroll
    for (int i = 0; i < 4; ++i)
        #pragma unroll
        for (int j = 0; j < 8; ++j) acc[i][j] = (f32x4)0.0f;

    float4 pA[4];
    auto prefA = [&](int kc_) {
        const int o = kc_ * 32;
        pA[0] = *(const float4*)(zA0 + o);
        pA[1] = *(const float4*)(zA0 + o + 4);
        pA[2] = *(const float4*)(zA1 + o);
        pA[3] = *(const float4*)(zA1 + o + 4);
    };
    auto issueB = [&](int kc_, int buf) {
        unsigned short* bh = BhB + buf * 8192;
        unsigned short* bl = BlB + buf * 8192;
        #pragma unroll
        for (int i = 0; i < 4; ++i) {
            load_lds16(e_hi + gBh[i] + kc_ * 32, bh + lBo[i]);
            load_lds16(e_lo + gBl[i] + kc_ * 32, bl + lBo[i]);
        }
    };

    prefA(0);
    issueB(0, 0);

    for (int kc = 0; kc < 8; ++kc) {
        __syncthreads();     // (1) drains B(kc) loads — issued a full compute phase ago
        {   // A: split in regs -> LDS writes
            uint4 h0, l0, h1, l1;
            split8(pA[0], pA[1], h0, l0);
            split8(pA[2], pA[3], h1, l1);
            *(uint4*)(Ah + offA0) = h0; *(uint4*)(Al + offA0) = l0;
            *(uint4*)(Ah + offA1) = h1; *(uint4*)(Al + offA1) = l1;
        }
        __syncthreads();     // (2) A visible; vmcnt already drained -> cheap
        if (kc < 7) { prefA(kc + 1); issueB(kc + 1, (kc + 1) & 1); }

        const unsigned short* Bh_ = BhB + (kc & 1) * 8192;
        const unsigned short* Bl_ = BlB + (kc & 1) * 8192;
        bf16x8 ah[4], al[4];
        #pragma unroll
        for (int i = 0; i < 4; ++i) {
            ah[i] = __builtin_bit_cast(bf16x8, *(const uint4*)(Ah + offAf[i]));
            al[i] = __builtin_bit_cast(bf16x8, *(const uint4*)(Al + offAf[i]));
        }
        #pragma unroll
        for (int j = 0; j < 8; ++j) {
            const bf16x8 bh = __builtin_bit_cast(bf16x8, *(const uint4*)(Bh_ + offBf[j]));
            const bf16x8 bl = __builtin_bit_cast(bf16x8, *(const uint4*)(Bl_ + offBf[j]));
            #pragma unroll
            for (int i = 0; i < 4; ++i)
                acc[i][j] = __builtin_amdgcn_mfma_f32_16x16x32_bf16(ah[i], bh, acc[i][j], 0, 0, 0);
            #pragma unroll
            for (int i = 0; i < 4; ++i)
                acc[i][j] = __builtin_amdgcn_mfma_f32_16x16x32_bf16(al[i], bh, acc[i][j], 0, 0, 0);
            #pragma unroll
            for (int i = 0; i < 4; ++i)
                acc[i][j] = __builtin_amdgcn_mfma_f32_16x16x32_bf16(ah[i], bl, acc[i][j], 0, 0, 0);
        }
    }

    // ---- distances + in-thread argmin ----
    float bestd[4][4];
    int   besti[4][4];
    #pragma unroll
    for (int i = 0; i < 4; ++i)
        #pragma unroll
        for (int r = 0; r < 4; ++r) { bestd[i][r] = 3.4e38f; besti[i][r] = 0; }
    #pragma unroll
    for (int j = 0; j < 8; ++j) {
        const int col = col0 + wx * 128 + j * 16 + tx;
        const float en = enorm[col];
        #pragma unroll
        for (int i = 0; i < 4; ++i)
            #pragma unroll
            for (int r = 0; r < 4; ++r) {
                const float d = fmaf(-2.0f, acc[i][j][r], en);
                if (d < bestd[i][r] || (d == bestd[i][r] && col < besti[i][r])) {
                    bestd[i][r] = d; besti[i][r] = col;
                }
            }
    }

    // ---- butterfly over the 16 tx lanes ----
    #pragma unroll
    for (int m = 1; m < 16; m <<= 1) {
        #pragma unroll
        for (int i = 0; i < 4; ++i)
            #pragma unroll
            for (int r = 0; r < 4; ++r) {
                const float od = __shfl_xor(bestd[i][r], m);
                const int   oi = __shfl_xor(besti[i][r], m);
                if (od < bestd[i][r] || (od == bestd[i][r] && oi < besti[i][r])) {
                    bestd[i][r] = od; besti[i][r] = oi;
                }
            }
    }

    // ---- merge wx halves via LDS, write per-split best ----
    __syncthreads();
    float* mg_d = (float*)Ah;                 // [2][128]
    int*   mg_i = (int*)Ah + 256;
    if (tx == 0) {
        #pragma unroll
        for (int i = 0; i < 4; ++i)
            #pragma unroll
            for (int r = 0; r < 4; ++r) {
                const int rb = wy * 64 + i * 16 + quad * 4 + r;
                mg_d[wx * 128 + rb] = bestd[i][r];
                mg_i[wx * 128 + rb] = besti[i][r];
            }
    }
    __syncthreads();
    if (tid < 128) {
        float d0 = mg_d[tid];             int i0 = mg_i[tid];
        const float d1 = mg_d[128 + tid]; const int i1 = mg_i[128 + tid];
        if (d1 < d0 || (d1 == d0 && i1 < i0)) { d0 = d1; i0 = i1; }
        best_d[csp * 32768 + row0 + tid] = d0;
        best_i[csp * 32768 + row0 + tid] = i0;
    }
}

// ============ kernel 2: cooperative fused tail ============
// 512 blocks x 256 thr, all co-resident. Stages separated by grid.sync():
//   S1 merge splits -> idx/cnt + gather z_q
//   S2 scan (block 0): out_cs, csum, cursor
//   S3 scatter rows to code-sorted order
//   S4 dw run-length accumulate + algebraic loss
//   S5 EMA-w/embedding epilogue + loss finalize
struct TailArgs {
    const float* z; const float* emb; const float* enorm;
    const float* ema_cs; const float* ema_w;
    const float* best_d; const int* best_i;
    int* idx; float* idxf; float* out_zq;
    int* cnt; int* cursor; int* sorted;
    float* dwacc; float* lossbuf;
    float* out_cs; float* csum;
    float* out_emb; float* out_emaw; float* out_loss;
};

__global__ __launch_bounds__(256)
void tail_kernel(TailArgs a) {
    cg::grid_group grid = cg::this_grid();
    __shared__ int   s_wsum[4];
    __shared__ float s_wred[4];
    __shared__ float s_red[256];
    const int tid = threadIdx.x, lane = tid & 63, wv = tid >> 6;
    const int b = blockIdx.x;

    // ---- S1: merge + gather ----
    for (int it = 0; it < 16; ++it) {
        const int n = b * 64 + wv * 16 + it;
        float d = a.best_d[n]; int i0 = a.best_i[n];
        #pragma unroll
        for (int s = 1; s < 4; ++s) {
            const float ds = a.best_d[s * 32768 + n];
            const int   ii = a.best_i[s * 32768 + n];
            if (ds < d) { d = ds; i0 = ii; }      // splits ascend in code: strict <
        }
        if (lane == 0) { a.idx[n] = i0; a.idxf[n] = (float)i0; atomicAdd(&a.cnt[i0], 1); }
        const float4 e4 = *(const float4*)(a.emb + (size_t)i0 * 256 + lane * 4);
        *(float4*)(a.out_zq + (size_t)n * 256 + lane * 4) = e4;
    }
    grid.sync();

    // ---- S2: scan (block 0 only; 256 thr x 4 codes) ----
    if (b == 0) {
        const int k0 = tid * 4;
        const int c0 = a.cnt[k0], c1 = a.cnt[k0 + 1], c2 = a.cnt[k0 + 2], c3 = a.cnt[k0 + 3];
        const int e1 = c0, e2 = c0 + c1, e3 = e2 + c2, ts = e3 + c3;
        const float f0 = DECAY_F * a.ema_cs[k0]     + OMD_F * (float)c0;
        const float f1 = DECAY_F * a.ema_cs[k0 + 1] + OMD_F * (float)c1;
        const float f2 = DECAY_F * a.ema_cs[k0 + 2] + OMD_F * (float)c2;
        const float f3 = DECAY_F * a.ema_cs[k0 + 3] + OMD_F * (float)c3;
        a.out_cs[k0] = f0; a.out_cs[k0 + 1] = f1; a.out_cs[k0 + 2] = f2; a.out_cs[k0 + 3] = f3;
        float fs = f0 + f1 + f2 + f3;
        #pragma unroll
        for (int o = 32; o > 0; o >>= 1) fs += __shfl_down(fs, o);
        if (lane == 0) s_wred[wv] = fs;
        int v = ts;
        #pragma unroll
        for (int o = 1; o < 64; o <<= 1) { const int u = __shfl_up(v, o); if (lane >= o) v += u; }
        if (lane == 63) s_wsum[wv] = v;
        __syncthreads();
        int wbase = 0;
        #pragma unroll
        for (int w = 0; w < 4; ++w) if (w < wv) wbase += s_wsum[w];
        const int texcl = wbase + v - ts;
        a.cursor[k0] = texcl;          a.cursor[k0 + 1] = texcl + e1;
        a.cursor[k0 + 2] = texcl + e2; a.cursor[k0 + 3] = texcl + e3;
        if (tid == 0) a.csum[0] = s_wred[0] + s_wred[1] + s_wred[2] + s_wred[3];
    }
    grid.sync();

    // ---- S3: scatter ----
    {
        const int n = b * 256 + tid;
        if (n < 32768) {
            const int k = a.idx[n];
            const int p = atomicAdd(&a.cursor[k], 1);
            a.sorted[p] = n;
        }
    }
    grid.sync();

    // ---- S4: dw + loss (wave per 16 sorted rows, run-length flush) ----
    {
        const int w  = b * 4 + wv;        // 0..2047
        const int r0 = w * 16;
        int srow = 0, skey = 0;
        if (lane < 16) { srow = a.sorted[r0 + lane]; skey = a.idx[srow]; }
        float4 s = make_float4(0.f, 0.f, 0.f, 0.f);
        float sumsq = 0.f;
        int cntr = 0;
        int krun = __shfl(skey, 0);

        auto flush = [&](int k) {
            const float4 e = *(const float4*)(a.emb + (size_t)k * 256 + lane * 4);
            float val = sumsq - 2.0f * (e.x * s.x + e.y * s.y + e.z * s.z + e.w * s.w);
            #pragma unroll
            for (int off = 32; off > 0; off >>= 1) val += __shfl_down(val, off);
            if (lane == 0) atomicAdd(&a.lossbuf[k & 255], val + (float)cntr * a.enorm[k]);
            float* p = a.dwacc + (size_t)k * 256 + lane * 4;
            atomicAdd(p + 0, s.x); atomicAdd(p + 1, s.y);
            atomicAdd(p + 2, s.z); atomicAdd(p + 3, s.w);
        };

        #pragma unroll 4
        for (int j = 0; j < 16; ++j) {
            const int row = __shfl(srow, j);
            const int k   = __shfl(skey, j);
            if (k != krun) {
                flush(krun);
                s = make_float4(0.f, 0.f, 0.f, 0.f);
                sumsq = 0.f; cntr = 0; krun = k;
            }
            const float4 v = *(const float4*)(a.z + (size_t)row * 256 + lane * 4);
            s.x += v.x; s.y += v.y; s.z += v.z; s.w += v.w;
            sumsq += v.x * v.x + v.y * v.y + v.z * v.z + v.w * v.w;
            ++cntr;
        }
        flush(krun);
    }
    grid.sync();

    // ---- S5: EMA-w / embedding epilogue + loss finalize ----
    {
        const int g = b * 256 + tid;      // float4 slot
        if (g < 65536) {
            const int k = g >> 6;
            const float n_total = a.csum[0];
            const float cs = (a.out_cs[k] + EPS_F) / (n_total + 1024.0f * EPS_F) * n_total;
            const float4 w4 = *(const float4*)(a.ema_w + (size_t)g * 4);
            const float4 d4 = *(const float4*)(a.dwacc + (size_t)g * 4);
            float4 nw, ne;
            nw.x = DECAY_F * w4.x + OMD_F * d4.x;
            nw.y = DECAY_F * w4.y + OMD_F * d4.y;
            nw.z = DECAY_F * w4.z + OMD_F * d4.z;
            nw.w = DECAY_F * w4.w + OMD_F * d4.w;
            ne.x = nw.x / cs; ne.y = nw.y / cs; ne.z = nw.z / cs; ne.w = nw.w / cs;
            *(float4*)(a.out_emaw + (size_t)g * 4) = nw;
            *(float4*)(a.out_emb  + (size_t)g * 4) = ne;
        }
        if (b == 0) {
            s_red[tid] = a.lossbuf[tid];
            __syncthreads();
            #pragma unroll
            for (int off = 128; off > 0; off >>= 1) {
                if (tid < off) s_red[tid] += s_red[tid + off];
                __syncthreads();
            }
            if (tid == 0) a.out_loss[0] = 1.25f * s_red[0] / 8388608.0f;
        }
    }
}

// ======================= launcher =======================
extern "C" void kernel_launch(void* const* d_in, const int* in_sizes, int n_in,
                              void* d_out, int out_size, void* d_ws, size_t ws_size,
                              hipStream_t stream) {
    const float* z      = (const float*)d_in[0];
    const float* emb    = (const float*)d_in[1];
    const float* ema_cs = (const float*)d_in[2];
    const float* ema_w  = (const float*)d_in[3];

    float* out = (float*)d_out;
    char*  wsb = (char*)d_ws;

    int*            cnt     = (int*)(wsb + WSB_CNTI);
    float*          lossbuf = (float*)(wsb + WSB_LOSS);
    float*          dwacc   = (float*)(wsb + WSB_DWACC);
    float*          csum    = (float*)(wsb + WSB_CSUM);
    float*          enorm   = (float*)(wsb + WSB_ENORM);
    int*            idx     = (int*)(wsb + WSB_IDX);
    unsigned short* e_hi    = (unsigned short*)(wsb + WSB_EHI);
    unsigned short* e_lo    = (unsigned short*)(wsb + WSB_ELO);
    int*            sorted  = (int*)(wsb + WSB_SORT);
    int*            cursor  = (int*)(wsb + WSB_CURS);
    float*          best_d  = (float*)(wsb + WSB_BESTD);
    int*            best_i  = (int*)(wsb + WSB_BESTI);

    float* out_zq   = out + OUT_ZQ;
    float* out_loss = out + OUT_LOSS;
    float* out_idxf = out + OUT_IDX;
    float* out_emb  = out + OUT_EMB;
    float* out_cs   = out + OUT_CS;
    float* out_emaw = out + OUT_EMAW;

    // allow 80 KB dynamic LDS for argmin (idempotent host-side attribute)
    hipFuncSetAttribute(reinterpret_cast<const void*>(argmin_kernel),
                        hipFuncAttributeMaxDynamicSharedMemorySize, 81920);

    esplit_enorm_kernel<<<256, 256, 0, stream>>>(emb, e_hi, e_lo, enorm,
                                                 cnt, lossbuf, dwacc);
    argmin_kernel<<<1024, 256, 81920, stream>>>(z, e_hi, e_lo, enorm, best_d, best_i);

    TailArgs ta = {z, emb, enorm, ema_cs, ema_w, best_d, best_i,
                   idx, out_idxf, out_zq, cnt, cursor, sorted,
                   dwacc, lossbuf, out_cs, csum, out_emb, out_emaw, out_loss};
    void* args[] = {&ta};
    hipLaunchCooperativeKernel(reinterpret_cast<void*>(tail_kernel),
                               dim3(512), dim3(256), args, 0, stream);
}